// Round 1
// baseline (316.076 us; speedup 1.0000x reference)
//
#include <hip/hip_runtime.h>

#define B_ 8
#define T_ 4000
#define D_ 512
#define L_ 8922

typedef __attribute__((ext_vector_type(8))) short short8;     // 8 bf16 = 4 VGPR (MFMA A/B frag)
typedef __attribute__((ext_vector_type(4))) float float4v;    // 4 f32 (MFMA C/D frag)
typedef __attribute__((ext_vector_type(4))) unsigned short us4;

// round-to-nearest-even f32 -> bf16 (bit pattern)
__device__ inline unsigned short f2bf(float f) {
    unsigned u = __builtin_bit_cast(unsigned, f);
    return (unsigned short)((u + 0x7FFFu + ((u >> 16) & 1u)) >> 16);
}
__device__ inline float bf2f(unsigned short h) {
    unsigned u = ((unsigned)h) << 16;
    return __builtin_bit_cast(float, u);
}

// async global->LDS, 16B per lane. lds ptr: wave-uniform base + lane*16.
#define GLL(gp, lp)                                                            \
    __builtin_amdgcn_global_load_lds(                                          \
        (const __attribute__((address_space(1))) unsigned int*)(gp),           \
        (__attribute__((address_space(3))) unsigned int*)(lp), 16, 0, 0)

// ---------------------------------------------------------------------------
// Kernel 1: uh = bf16(U_w), vh = bf16(final_w * proj_w)   [L, D]
// ---------------------------------------------------------------------------
__global__ __launch_bounds__(256) void cast_uv(const float* __restrict__ Uw,
                                               const float* __restrict__ Fw,
                                               const float* __restrict__ Pw,
                                               unsigned short* __restrict__ uh,
                                               unsigned short* __restrict__ vh) {
    const int total4 = (L_ * D_) / 4;
    int i = blockIdx.x * 256 + threadIdx.x;
    if (i >= total4) return;
    const int base = i * 4;
    const int d = base & (D_ - 1);
    float4 u4 = *(const float4*)(Uw + base);
    float4 f4 = *(const float4*)(Fw + base);
    float4 p4 = *(const float4*)(Pw + d);
    us4 uo, vo;
    uo.x = f2bf(u4.x); uo.y = f2bf(u4.y); uo.z = f2bf(u4.z); uo.w = f2bf(u4.w);
    vo.x = f2bf(f4.x * p4.x); vo.y = f2bf(f4.y * p4.y);
    vo.z = f2bf(f4.z * p4.z); vo.w = f2bf(f4.w * p4.w);
    *(us4*)(uh + base) = uo;
    *(us4*)(vh + base) = vo;
}

// ---------------------------------------------------------------------------
// Kernel 2: xT[b][d][t] = bf16(x[b][t][d])  (LDS-tiled 32x32 transpose)
// ---------------------------------------------------------------------------
__global__ __launch_bounds__(256) void transpose_x(const float* __restrict__ x,
                                                   unsigned short* __restrict__ xT) {
    __shared__ float tile[32][33];
    const int b = blockIdx.z;
    const int t0 = blockIdx.x * 32;
    const int d0 = blockIdx.y * 32;
    const int tx = threadIdx.x & 31, ty = threadIdx.x >> 5;  // ty: 0..7
#pragma unroll
    for (int k = 0; k < 4; k++)
        tile[ty + 8 * k][tx] = x[(size_t)(b * T_ + t0 + ty + 8 * k) * D_ + d0 + tx];
    __syncthreads();
#pragma unroll
    for (int k = 0; k < 4; k++)
        xT[(size_t)(b * D_ + d0 + ty + 8 * k) * T_ + t0 + tx] = f2bf(tile[tx][ty + 8 * k]);
}

// ---------------------------------------------------------------------------
// Kernel 3: Sh[b] = bf16( x_b^T @ x_b )   [D, D], MFMA 16x16x32 bf16
// 128x128 tile / wg, 4 waves (2x2), BK=32, single-buffered LDS.
// Both operands are the SAME transposed-pattern read of xT (A-frag and B-frag
// lane layouts are row/col symmetric), so one loader serves both.
// ---------------------------------------------------------------------------
__global__ __launch_bounds__(256) void gram(const unsigned short* __restrict__ xT,
                                            unsigned short* __restrict__ Sh) {
    __shared__ __align__(16) unsigned short lA[128 * 32];
    __shared__ __align__(16) unsigned short lB[128 * 32];
    const int tid = threadIdx.x;
    const int b = blockIdx.y;
    const int i0 = (blockIdx.x >> 2) * 128;
    const int j0 = (blockIdx.x & 3) * 128;
    const int l = tid & 63;
    const int wv = tid >> 6;
    const int wr = wv >> 1, wc = wv & 1;
    const int lr = l & 15, lg = l >> 4;

    const float4v z4 = {0.f, 0.f, 0.f, 0.f};
    float4v acc[4][4];
#pragma unroll
    for (int m = 0; m < 4; m++)
#pragma unroll
        for (int n = 0; n < 4; n++) acc[m][n] = z4;

    const size_t xb = (size_t)b * D_ * T_;
    const int srow = tid >> 2;          // 0..63
    const int scol = (tid & 3) * 8;     // element offset in row
    const unsigned short* gA0 = xT + xb + (size_t)(i0 + srow) * T_ + scol;
    const unsigned short* gA1 = xT + xb + (size_t)(i0 + 64 + srow) * T_ + scol;
    const unsigned short* gB0 = xT + xb + (size_t)(j0 + srow) * T_ + scol;
    const unsigned short* gB1 = xT + xb + (size_t)(j0 + 64 + srow) * T_ + scol;

    for (int kt = 0; kt < T_; kt += 32) {
        GLL(gA0 + kt, &lA[tid * 8]);
        GLL(gA1 + kt, &lA[2048 + tid * 8]);
        GLL(gB0 + kt, &lB[tid * 8]);
        GLL(gB1 + kt, &lB[2048 + tid * 8]);
        asm volatile("s_waitcnt vmcnt(0)" ::: "memory");
        __syncthreads();
        short8 af[4], bf[4];
#pragma unroll
        for (int m = 0; m < 4; m++)
            af[m] = *(const short8*)&lA[(wr * 64 + m * 16 + lr) * 32 + lg * 8];
#pragma unroll
        for (int n = 0; n < 4; n++)
            bf[n] = *(const short8*)&lB[(wc * 64 + n * 16 + lr) * 32 + lg * 8];
#pragma unroll
        for (int m = 0; m < 4; m++)
#pragma unroll
            for (int n = 0; n < 4; n++)
                acc[m][n] = __builtin_amdgcn_mfma_f32_16x16x32_bf16(af[m], bf[n], acc[m][n], 0, 0, 0);
        __syncthreads();
    }

    const size_t sb = (size_t)b * D_ * D_;
#pragma unroll
    for (int m = 0; m < 4; m++)
#pragma unroll
        for (int n = 0; n < 4; n++)
#pragma unroll
            for (int r = 0; r < 4; r++) {
                int row = i0 + wr * 64 + m * 16 + lg * 4 + r;
                int col = j0 + wc * 64 + n * 16 + lr;
                Sh[sb + (size_t)row * D_ + col] = f2bf(acc[m][n][r]);
            }
}

// ---------------------------------------------------------------------------
// Kernel 4: out[b][l] = final_b[l]
// ---------------------------------------------------------------------------
__global__ __launch_bounds__(256) void init_out(const float* __restrict__ fb,
                                                float* __restrict__ out) {
    int lk = blockIdx.x * 256 + threadIdx.x;
    int b = blockIdx.y;
    if (lk < L_) out[(size_t)b * L_ + lk] = fb[lk];
}

// ---------------------------------------------------------------------------
// Kernel 5: logits[b,l] += sum_d (U @ S_b)[l,d] * vh[l,d]
// GEMM tile 128(l) x 128(d), K=512(d'), fused v-dot epilogue + atomicAdd.
// B-operand = S_b read ROW-major exploiting S symmetry (no transpose needed).
// ---------------------------------------------------------------------------
__global__ __launch_bounds__(256) void stage2(const unsigned short* __restrict__ uh,
                                              const unsigned short* __restrict__ vh,
                                              const unsigned short* __restrict__ Sh,
                                              float* __restrict__ out) {
    __shared__ __align__(16) unsigned short lA[128 * 32];
    __shared__ __align__(16) unsigned short lB[128 * 32];
    __shared__ float red[2][128];
    const int tid = threadIdx.x;
    const int b = blockIdx.y;
    const int lt = blockIdx.x >> 2;
    const int dt = blockIdx.x & 3;
    const int l0 = lt * 128, d0 = dt * 128;
    const int l = tid & 63;
    const int wv = tid >> 6;
    const int wr = wv >> 1, wc = wv & 1;
    const int lr = l & 15, lg = l >> 4;

    const float4v z4 = {0.f, 0.f, 0.f, 0.f};
    float4v acc[4][4];
#pragma unroll
    for (int m = 0; m < 4; m++)
#pragma unroll
        for (int n = 0; n < 4; n++) acc[m][n] = z4;

    const int srow = tid >> 2;
    const int scol = (tid & 3) * 8;
    const int rA0 = min(l0 + srow, L_ - 1);        // clamp tail rows (discarded later)
    const int rA1 = min(l0 + 64 + srow, L_ - 1);
    const unsigned short* gA0 = uh + (size_t)rA0 * D_ + scol;
    const unsigned short* gA1 = uh + (size_t)rA1 * D_ + scol;
    const size_t sb = (size_t)b * D_ * D_;
    const unsigned short* gB0 = Sh + sb + (size_t)(d0 + srow) * D_ + scol;
    const unsigned short* gB1 = Sh + sb + (size_t)(d0 + 64 + srow) * D_ + scol;

    for (int kt = 0; kt < D_; kt += 32) {
        GLL(gA0 + kt, &lA[tid * 8]);
        GLL(gA1 + kt, &lA[2048 + tid * 8]);
        GLL(gB0 + kt, &lB[tid * 8]);
        GLL(gB1 + kt, &lB[2048 + tid * 8]);
        asm volatile("s_waitcnt vmcnt(0)" ::: "memory");
        __syncthreads();
        short8 af[4], bf[4];
#pragma unroll
        for (int m = 0; m < 4; m++)
            af[m] = *(const short8*)&lA[(wr * 64 + m * 16 + lr) * 32 + lg * 8];
#pragma unroll
        for (int n = 0; n < 4; n++)
            bf[n] = *(const short8*)&lB[(wc * 64 + n * 16 + lr) * 32 + lg * 8];
#pragma unroll
        for (int m = 0; m < 4; m++)
#pragma unroll
            for (int n = 0; n < 4; n++)
                acc[m][n] = __builtin_amdgcn_mfma_f32_16x16x32_bf16(af[m], bf[n], acc[m][n], 0, 0, 0);
        __syncthreads();
    }

    // epilogue: multiply by vh[l,d], reduce over d
    float part[4][4];
#pragma unroll
    for (int m = 0; m < 4; m++)
#pragma unroll
        for (int r = 0; r < 4; r++) part[m][r] = 0.f;
#pragma unroll
    for (int m = 0; m < 4; m++)
#pragma unroll
        for (int n = 0; n < 4; n++) {
            int dcol = d0 + wc * 64 + n * 16 + lr;
#pragma unroll
            for (int r = 0; r < 4; r++) {
                int lrow = l0 + wr * 64 + m * 16 + lg * 4 + r;
                float v = bf2f(vh[(size_t)min(lrow, L_ - 1) * D_ + dcol]);
                part[m][r] += acc[m][n][r] * v;
            }
        }
    // reduce over the 16 lanes (lr) holding different d columns
#pragma unroll
    for (int off = 1; off < 16; off <<= 1)
#pragma unroll
        for (int m = 0; m < 4; m++)
#pragma unroll
            for (int r = 0; r < 4; r++)
                part[m][r] += __shfl_xor(part[m][r], off, 64);
    if (lr == 0) {
#pragma unroll
        for (int m = 0; m < 4; m++)
#pragma unroll
            for (int r = 0; r < 4; r++)
                red[wc][wr * 64 + m * 16 + lg * 4 + r] = part[m][r];
    }
    __syncthreads();
    if (tid < 128) {
        int lrow = l0 + tid;
        if (lrow < L_) atomicAdd(&out[(size_t)b * L_ + lrow], red[0][tid] + red[1][tid]);
    }
}

// ---------------------------------------------------------------------------
extern "C" void kernel_launch(void* const* d_in, const int* in_sizes, int n_in,
                              void* d_out, int out_size, void* d_ws, size_t ws_size,
                              hipStream_t stream) {
    const float* x  = (const float*)d_in[0];
    const float* Uw = (const float*)d_in[1];
    const float* Fw = (const float*)d_in[2];
    const float* fb = (const float*)d_in[3];
    const float* Pw = (const float*)d_in[4];
    float* out = (float*)d_out;

    char* ws = (char*)d_ws;
    unsigned short* xT = (unsigned short*)(ws);                 // 32,768,000 B
    unsigned short* uh = (unsigned short*)(ws + 32768000);      //  9,136,128 B
    unsigned short* vh = (unsigned short*)(ws + 41904128);      //  9,136,128 B
    unsigned short* Sh = (unsigned short*)(ws + 51040256);      //  4,194,304 B  (total ~55.2 MB)

    hipLaunchKernelGGL(cast_uv, dim3((L_ * D_ / 4 + 255) / 256), dim3(256), 0, stream,
                       Uw, Fw, Pw, uh, vh);
    hipLaunchKernelGGL(transpose_x, dim3(T_ / 32, D_ / 32, B_), dim3(256), 0, stream, x, xT);
    hipLaunchKernelGGL(gram, dim3(16, B_), dim3(256), 0, stream, xT, Sh);
    hipLaunchKernelGGL(init_out, dim3((L_ + 255) / 256, B_), dim3(256), 0, stream, fb, out);
    hipLaunchKernelGGL(stage2, dim3(280, B_), dim3(256), 0, stream, uh, vh, Sh, out);
}

// Round 2
// 261.108 us; speedup vs baseline: 1.2105x; 1.2105x over previous
//
#include <hip/hip_runtime.h>

#define B_ 8
#define T_ 4000
#define D_ 512
#define L_ 8922
#define KSPLIT 8
#define KSTEPS_TOT 125   // T_/32
#define KCH 16           // K-steps per split chunk (last chunk = 13)

typedef __attribute__((ext_vector_type(8))) short short8;     // 8 bf16 (MFMA A/B frag)
typedef __attribute__((ext_vector_type(4))) float float4v;    // 4 f32 (MFMA C/D frag)
typedef __attribute__((ext_vector_type(4))) unsigned short us4;

__device__ inline unsigned short f2bf(float f) {
    unsigned u = __builtin_bit_cast(unsigned, f);
    return (unsigned short)((u + 0x7FFFu + ((u >> 16) & 1u)) >> 16);
}
__device__ inline float bf2f(unsigned short h) {
    unsigned u = ((unsigned)h) << 16;
    return __builtin_bit_cast(float, u);
}

// async global->LDS, 16B per lane; LDS dest = wave-uniform base + lane*16 (linear).
#define GLL(gp, lp)                                                            \
    __builtin_amdgcn_global_load_lds(                                          \
        (const __attribute__((address_space(1))) unsigned int*)(gp),           \
        (__attribute__((address_space(3))) unsigned int*)(lp), 16, 0, 0)

// Swizzled LDS offset (ushort units) of (row 0..127, 16B-chunk lg 0..3) in a
// [128 rows x 32 bf16] tile. Layout: row-pairs share a 128B line; chunk index
// XOR'd with (pair&3). A wave's 64-lane b128 frag read touches 64 distinct
// 16B slots -> conflict-free. GLL writes stay linear; the *global source*
// address is pre-swizzled to match (both-sides-or-neither).
__device__ inline int swz(int row, int lg) {
    return ((row >> 1) << 6) + ((row & 1) << 5) + ((lg ^ ((row >> 1) & 3)) << 3);
}

// ---------------------------------------------------------------------------
// Kernel 1: uh = bf16(U_w), vh = bf16(final_w * proj_w)   [L, D]
// ---------------------------------------------------------------------------
__global__ __launch_bounds__(256) void cast_uv(const float* __restrict__ Uw,
                                               const float* __restrict__ Fw,
                                               const float* __restrict__ Pw,
                                               unsigned short* __restrict__ uh,
                                               unsigned short* __restrict__ vh) {
    const int total4 = (L_ * D_) / 4;
    int i = blockIdx.x * 256 + threadIdx.x;
    if (i >= total4) return;
    const int base = i * 4;
    const int d = base & (D_ - 1);
    float4 u4 = *(const float4*)(Uw + base);
    float4 f4 = *(const float4*)(Fw + base);
    float4 p4 = *(const float4*)(Pw + d);
    us4 uo, vo;
    uo.x = f2bf(u4.x); uo.y = f2bf(u4.y); uo.z = f2bf(u4.z); uo.w = f2bf(u4.w);
    vo.x = f2bf(f4.x * p4.x); vo.y = f2bf(f4.y * p4.y);
    vo.z = f2bf(f4.z * p4.z); vo.w = f2bf(f4.w * p4.w);
    *(us4*)(uh + base) = uo;
    *(us4*)(vh + base) = vo;
}

// ---------------------------------------------------------------------------
// Kernel 2: xT[b][d][t] = bf16(x[b][t][d])  (LDS-tiled 32x32 transpose)
// ---------------------------------------------------------------------------
__global__ __launch_bounds__(256) void transpose_x(const float* __restrict__ x,
                                                   unsigned short* __restrict__ xT) {
    __shared__ float tile[32][33];
    const int b = blockIdx.z;
    const int t0 = blockIdx.x * 32;
    const int d0 = blockIdx.y * 32;
    const int tx = threadIdx.x & 31, ty = threadIdx.x >> 5;
#pragma unroll
    for (int k = 0; k < 4; k++)
        tile[ty + 8 * k][tx] = x[(size_t)(b * T_ + t0 + ty + 8 * k) * D_ + d0 + tx];
    __syncthreads();
#pragma unroll
    for (int k = 0; k < 4; k++)
        xT[(size_t)(b * D_ + d0 + ty + 8 * k) * T_ + t0 + tx] = f2bf(tile[tx][ty + 8 * k]);
}

// ---------------------------------------------------------------------------
// Kernel 3: split-K symmetric Gram partials: Sf[b] += x_b^T x_b (upper tiles)
// grid.x = 8(batch, inner for XCD-L2 locality) * 10(sym tiles) * 8(K-split)
// 128x128 tile / 4 waves, BK=32, double-buffered prefetch 2-phase,
// swizzled LDS (conflict-free frag reads), f32 atomicAdd epilogue.
// ---------------------------------------------------------------------------
__global__ __launch_bounds__(256) void gramk(const unsigned short* __restrict__ xT,
                                             float* __restrict__ Sf) {
    __shared__ __align__(16) unsigned short lA[2][4096];
    __shared__ __align__(16) unsigned short lB[2][4096];
    const int tid = threadIdx.x;
    const int bid = blockIdx.x;
    const int b = bid & 7;
    const int r2 = bid >> 3;            // 0..79
    const int tile = r2 % 10;
    const int ks = r2 / 10;             // 0..7
    int ti, tj;
    if (tile < 4)      { ti = 0; tj = tile; }
    else if (tile < 7) { ti = 1; tj = tile - 3; }
    else if (tile < 9) { ti = 2; tj = tile - 5; }
    else               { ti = 3; tj = 3; }
    const int i0 = ti * 128, j0 = tj * 128;
    const int kbeg = ks * KCH;
    const int nst = min(KSTEPS_TOT, kbeg + KCH) - kbeg;

    const int l = tid & 63;
    const int wv = tid >> 6, wr = wv >> 1, wc = wv & 1;
    const int lr = l & 15, lg = l >> 4;

    const float4v z4 = {0.f, 0.f, 0.f, 0.f};
    float4v acc[4][4];
#pragma unroll
    for (int m = 0; m < 4; m++)
#pragma unroll
        for (int n = 0; n < 4; n++) acc[m][n] = z4;

    // staging: thread tid writes LDS linear slot tid*16B; matching source is
    // row rl = 2*(tid>>3)+((tid>>2)&1), chunk (tid&3)^((tid>>3)&3).
    const int rl = ((tid >> 3) << 1) | ((tid >> 2) & 1);
    const int sc = ((tid & 3) ^ ((tid >> 3) & 3)) << 3;
    const size_t xb = (size_t)b * D_ * T_;
    const unsigned short* gA0 = xT + xb + (size_t)(i0 + rl) * T_ + kbeg * 32 + sc;
    const unsigned short* gA1 = xT + xb + (size_t)(i0 + 64 + rl) * T_ + kbeg * 32 + sc;
    const unsigned short* gB0 = xT + xb + (size_t)(j0 + rl) * T_ + kbeg * 32 + sc;
    const unsigned short* gB1 = xT + xb + (size_t)(j0 + 64 + rl) * T_ + kbeg * 32 + sc;

#define STAGE_G(bf_, ko_)                                                      \
    {                                                                          \
        GLL(gA0 + (ko_), &lA[bf_][tid * 8]);                                   \
        GLL(gA1 + (ko_), &lA[bf_][2048 + tid * 8]);                            \
        GLL(gB0 + (ko_), &lB[bf_][tid * 8]);                                   \
        GLL(gB1 + (ko_), &lB[bf_][2048 + tid * 8]);                            \
    }

    STAGE_G(0, 0);
    asm volatile("s_waitcnt vmcnt(0)" ::: "memory");
    __syncthreads();
    for (int s = 0; s < nst; s++) {
        const int cur = s & 1;
        if (s + 1 < nst) STAGE_G(cur ^ 1, (s + 1) * 32);
        short8 af[4], bfr[4];
#pragma unroll
        for (int m = 0; m < 4; m++)
            af[m] = *(const short8*)&lA[cur][swz(wr * 64 + m * 16 + lr, lg)];
#pragma unroll
        for (int n = 0; n < 4; n++)
            bfr[n] = *(const short8*)&lB[cur][swz(wc * 64 + n * 16 + lr, lg)];
#pragma unroll
        for (int m = 0; m < 4; m++)
#pragma unroll
            for (int n = 0; n < 4; n++)
                acc[m][n] = __builtin_amdgcn_mfma_f32_16x16x32_bf16(af[m], bfr[n], acc[m][n], 0, 0, 0);
        asm volatile("s_waitcnt vmcnt(0)" ::: "memory");
        __syncthreads();
    }
#undef STAGE_G

    float* Sb = Sf + (size_t)b * D_ * D_;
#pragma unroll
    for (int m = 0; m < 4; m++)
#pragma unroll
        for (int n = 0; n < 4; n++)
#pragma unroll
            for (int r = 0; r < 4; r++) {
                int row = i0 + wr * 64 + m * 16 + lg * 4 + r;
                int col = j0 + wc * 64 + n * 16 + lr;
                atomicAdd(&Sb[(size_t)row * D_ + col], acc[m][n][r]);
            }
}

// ---------------------------------------------------------------------------
// Kernel 4: Sh = bf16(dense S) from upper-tile Sf, mirroring lower tiles.
// ---------------------------------------------------------------------------
__global__ __launch_bounds__(256) void castS(const float* __restrict__ Sf,
                                             unsigned short* __restrict__ Sh) {
    int idx = blockIdx.x * 256 + threadIdx.x;          // B*D*D/4 threads
    int e = idx & (D_ * D_ / 4 - 1);
    int b = idx >> 16;                                 // D*D/4 = 65536
    int row = e >> 7;
    int col = (e & 127) << 2;
    const float* Sb = Sf + (size_t)b * D_ * D_;
    float4 v;
    if ((row >> 7) <= (col >> 7)) {
        v = *(const float4*)(Sb + (size_t)row * D_ + col);
    } else {
        v.x = Sb[(size_t)(col + 0) * D_ + row];
        v.y = Sb[(size_t)(col + 1) * D_ + row];
        v.z = Sb[(size_t)(col + 2) * D_ + row];
        v.w = Sb[(size_t)(col + 3) * D_ + row];
    }
    us4 o;
    o.x = f2bf(v.x); o.y = f2bf(v.y); o.z = f2bf(v.z); o.w = f2bf(v.w);
    *(us4*)(Sh + (size_t)b * D_ * D_ + (size_t)row * D_ + col) = o;
}

// ---------------------------------------------------------------------------
// Kernel 5: out[b][l] = final_b[l]
// ---------------------------------------------------------------------------
__global__ __launch_bounds__(256) void init_out(const float* __restrict__ fb,
                                                float* __restrict__ out) {
    int lk = blockIdx.x * 256 + threadIdx.x;
    int b = blockIdx.y;
    if (lk < L_) out[(size_t)b * L_ + lk] = fb[lk];
}

// ---------------------------------------------------------------------------
// Kernel 6: logits[b,l] += sum_d (U @ S_b)[l,d] * vh[l,d]
// 128(l)x128(d) tile, K=512, dbuf prefetch 2-phase + swizzled LDS,
// fused v-dot epilogue + atomicAdd. B-operand = S_b row-major (symmetry).
// ---------------------------------------------------------------------------
__global__ __launch_bounds__(256) void stage2(const unsigned short* __restrict__ uh,
                                              const unsigned short* __restrict__ vh,
                                              const unsigned short* __restrict__ Sh,
                                              float* __restrict__ out) {
    __shared__ __align__(16) unsigned short lA[2][4096];
    __shared__ __align__(16) unsigned short lB[2][4096];
    __shared__ float red[2][128];
    const int tid = threadIdx.x;
    const int b = blockIdx.y;
    const int lt = blockIdx.x >> 2;
    const int dt = blockIdx.x & 3;
    const int l0 = lt * 128, d0 = dt * 128;
    const int l = tid & 63;
    const int wv = tid >> 6, wr = wv >> 1, wc = wv & 1;
    const int lr = l & 15, lg = l >> 4;

    const float4v z4 = {0.f, 0.f, 0.f, 0.f};
    float4v acc[4][4];
#pragma unroll
    for (int m = 0; m < 4; m++)
#pragma unroll
        for (int n = 0; n < 4; n++) acc[m][n] = z4;

    const int rl = ((tid >> 3) << 1) | ((tid >> 2) & 1);
    const int sc = ((tid & 3) ^ ((tid >> 3) & 3)) << 3;
    const int rA0 = min(l0 + rl, L_ - 1);
    const int rA1 = min(l0 + 64 + rl, L_ - 1);
    const unsigned short* gA0 = uh + (size_t)rA0 * D_ + sc;
    const unsigned short* gA1 = uh + (size_t)rA1 * D_ + sc;
    const size_t sb = (size_t)b * D_ * D_;
    const unsigned short* gB0 = Sh + sb + (size_t)(d0 + rl) * D_ + sc;
    const unsigned short* gB1 = Sh + sb + (size_t)(d0 + 64 + rl) * D_ + sc;

#define STAGE_S(bf_, ko_)                                                      \
    {                                                                          \
        GLL(gA0 + (ko_), &lA[bf_][tid * 8]);                                   \
        GLL(gA1 + (ko_), &lA[bf_][2048 + tid * 8]);                            \
        GLL(gB0 + (ko_), &lB[bf_][tid * 8]);                                   \
        GLL(gB1 + (ko_), &lB[bf_][2048 + tid * 8]);                            \
    }

    STAGE_S(0, 0);
    asm volatile("s_waitcnt vmcnt(0)" ::: "memory");
    __syncthreads();
    for (int s = 0; s < 16; s++) {
        const int cur = s & 1;
        if (s + 1 < 16) STAGE_S(cur ^ 1, (s + 1) * 32);
        short8 af[4], bfr[4];
#pragma unroll
        for (int m = 0; m < 4; m++)
            af[m] = *(const short8*)&lA[cur][swz(wr * 64 + m * 16 + lr, lg)];
#pragma unroll
        for (int n = 0; n < 4; n++)
            bfr[n] = *(const short8*)&lB[cur][swz(wc * 64 + n * 16 + lr, lg)];
#pragma unroll
        for (int m = 0; m < 4; m++)
#pragma unroll
            for (int n = 0; n < 4; n++)
                acc[m][n] = __builtin_amdgcn_mfma_f32_16x16x32_bf16(af[m], bfr[n], acc[m][n], 0, 0, 0);
        asm volatile("s_waitcnt vmcnt(0)" ::: "memory");
        __syncthreads();
    }
#undef STAGE_S

    // epilogue: multiply by vh[l,d], reduce over d
    float part[4][4];
#pragma unroll
    for (int m = 0; m < 4; m++)
#pragma unroll
        for (int r = 0; r < 4; r++) part[m][r] = 0.f;
#pragma unroll
    for (int m = 0; m < 4; m++)
#pragma unroll
        for (int n = 0; n < 4; n++) {
            int dcol = d0 + wc * 64 + n * 16 + lr;
#pragma unroll
            for (int r = 0; r < 4; r++) {
                int lrow = l0 + wr * 64 + m * 16 + lg * 4 + r;
                float v = bf2f(vh[(size_t)min(lrow, L_ - 1) * D_ + dcol]);
                part[m][r] += acc[m][n][r] * v;
            }
        }
#pragma unroll
    for (int off = 1; off < 16; off <<= 1)
#pragma unroll
        for (int m = 0; m < 4; m++)
#pragma unroll
            for (int r = 0; r < 4; r++)
                part[m][r] += __shfl_xor(part[m][r], off, 64);
    if (lr == 0) {
#pragma unroll
        for (int m = 0; m < 4; m++)
#pragma unroll
            for (int r = 0; r < 4; r++)
                red[wc][wr * 64 + m * 16 + lg * 4 + r] = part[m][r];
    }
    __syncthreads();
    if (tid < 128) {
        int lrow = l0 + tid;
        if (lrow < L_) atomicAdd(&out[(size_t)b * L_ + lrow], red[0][tid] + red[1][tid]);
    }
}

// ---------------------------------------------------------------------------
extern "C" void kernel_launch(void* const* d_in, const int* in_sizes, int n_in,
                              void* d_out, int out_size, void* d_ws, size_t ws_size,
                              hipStream_t stream) {
    const float* x  = (const float*)d_in[0];
    const float* Uw = (const float*)d_in[1];
    const float* Fw = (const float*)d_in[2];
    const float* fb = (const float*)d_in[3];
    const float* Pw = (const float*)d_in[4];
    float* out = (float*)d_out;

    char* ws = (char*)d_ws;
    unsigned short* xT = (unsigned short*)(ws);                 // 32,768,000 B
    unsigned short* uh = (unsigned short*)(ws + 32768000);      //  9,136,128 B
    unsigned short* vh = (unsigned short*)(ws + 41904128);      //  9,136,128 B
    unsigned short* Sh = (unsigned short*)(ws + 51040256);      //  4,194,304 B
    float*          Sf = (float*)(ws + 55234560);               //  8,388,608 B (total ~63.6 MB)

    hipMemsetAsync(Sf, 0, (size_t)B_ * D_ * D_ * 4, stream);
    hipLaunchKernelGGL(cast_uv, dim3((L_ * D_ / 4 + 255) / 256), dim3(256), 0, stream,
                       Uw, Fw, Pw, uh, vh);
    hipLaunchKernelGGL(transpose_x, dim3(T_ / 32, D_ / 32, B_), dim3(256), 0, stream, x, xT);
    hipLaunchKernelGGL(gramk, dim3(8 * 10 * KSPLIT), dim3(256), 0, stream, xT, Sf);
    hipLaunchKernelGGL(castS, dim3(B_ * D_ * D_ / 4 / 256), dim3(256), 0, stream, Sf, Sh);
    hipLaunchKernelGGL(init_out, dim3((L_ + 255) / 256, B_), dim3(256), 0, stream, fb, out);
    hipLaunchKernelGGL(stage2, dim3(280, B_), dim3(256), 0, stream, uh, vh, Sh, out);
}